// Round 12
// baseline (77.841 us; speedup 1.0000x reference)
//
#include <hip/hip_runtime.h>
#include <math.h>

#define BB 8
#define SS 2048
#define DD 1024
#define MM 4096
#define dd 256
#define NCH 64          // S-chunks for x column-sum
#define CS (SS/NCH)     // 32 rows per chunk

typedef float f4 __attribute__((ext_vector_type(4)));

// ---- ws layout (floats) ----
#define OFF_PART  0                        // [b*64+chunk][1024] = 524288
#define OFF_Q     524288                   // 2048
#define OFF_WV    526336                   // 2048
#define OFF_GATE  528384                   // 8
#define OFF_COMBO 528392                   // 8
#define OFF_SUMP  528400                   // 2048: [which*1024 + b*128 + mc]
#define OFF_SC    530448                   // 32768: exp write-scores [b][m]
#define OFF_PRET  563216                   // 262144: [(b*128+mc)*256 + j]
#define OFF_ROUT  825360                   // 8192

// K1: x partial column sums. grid = B*NCH = 512, block 256, f4/thread.
__global__ void k1(const float* __restrict__ x, float* __restrict__ ws) {
    int blk = blockIdx.x;
    int chunk = blk & 63;
    int b = blk >> 6;
    int t = threadIdx.x;
    const f4* x4 = (const f4*)(x + ((size_t)b*SS + (size_t)chunk*CS)*DD);
    f4 a = (f4)(0.f);
    #pragma unroll
    for (int s = 0; s < CS; ++s) a += x4[s*256 + t];
    ((f4*)(ws + OFF_PART))[(size_t)blk*256 + t] = a;
}

// K23: fused projections + gate. grid = 72 blocks, block 512. (proven)
__global__ void k23(const float* __restrict__ Wq, const float* __restrict__ bq,
                    const float* __restrict__ Wv, const float* __restrict__ bv,
                    const float* __restrict__ Wg, const float* __restrict__ bg,
                    float* __restrict__ ws) {
    __shared__ f4 xsA[256];
    __shared__ f4 xsB[256];
    __shared__ float red[512];
    int blk = blockIdx.x;
    int t = threadIdx.x;
    const f4* p4 = (const f4*)(ws + OFF_PART);
    if (blk < 64) {
        int cs = blk & 3;
        int wb = blk >> 2;
        int b = wb & 7;
        int which = wb >> 3;
        int col4 = t & 255;
        int half = t >> 8;
        f4 a = (f4)(0.f);
        #pragma unroll 8
        for (int c = 0; c < 32; ++c)
            a += p4[(size_t)(b*NCH + half*32 + c)*256 + col4];
        if (half == 0) xsA[col4] = a; else xsB[col4] = a;
        __syncthreads();
        if (t < 256) xsA[t] = (xsA[t] + xsB[t]) * (1.f/SS);
        __syncthreads();
        const float* xs = (const float*)xsA;
        const float* W = which ? Wv : Wq;
        int kg = t >> 6;
        int c0 = cs*64 + (t & 63);
        float acc = 0.f;
        #pragma unroll 8
        for (int kk = 0; kk < 128; ++kk) {
            int k = kg*128 + kk;
            acc += xs[k] * W[(size_t)k*dd + c0];
        }
        red[t] = acc;
        __syncthreads();
        if (t < 64) {
            int c = cs*64 + t;
            float o = red[t] + red[t+64] + red[t+128] + red[t+192]
                    + red[t+256] + red[t+320] + red[t+384] + red[t+448];
            o += which ? bv[c] : bq[c];
            ws[(which ? OFF_WV : OFF_Q) + b*dd + c] = o;
        }
    } else {
        int b = blk - 64;
        const float* base = ws + OFF_PART + (size_t)(b*NCH)*DD;
        float wg0 = Wg[t], wg1 = Wg[t + 512];
        float acc = 0.f;
        #pragma unroll 8
        for (int c = 0; c < NCH; ++c) {
            const float* p = base + (size_t)c*DD;
            acc += p[t]*wg0 + p[t+512]*wg1;
        }
        red[t] = acc; __syncthreads();
        for (int s2 = 256; s2 > 0; s2 >>= 1) {
            if (t < s2) red[t] += red[t + s2];
            __syncthreads();
        }
        if (t == 0)
            ws[OFF_GATE + b] = 1.f / (1.f + __expf(-(red[0]*(1.f/SS) + bg[0])));
    }
}

// K45: scores+exp+rowsum-partials+retrieval-partials. 32-row chunks. grid = 2048.
__global__ __launch_bounds__(256, 8)
void k45(const float* __restrict__ memory, float* __restrict__ ws) {
    __shared__ float esc[32];
    int blk = blockIdx.x;
    int which = blk >> 10;
    int b = (blk >> 7) & 7;
    int mc = blk & 127;
    int t = threadIdx.x;
    int wave = t >> 6, lane = t & 63;
    const float* tile = ((which == 0) ? memory : memory + (size_t)b*MM*dd)
                        + (size_t)mc*32*dd;
    const f4 qv = ((const f4*)(ws + OFF_Q + b*dd))[lane];
    #pragma unroll
    for (int i = 0; i < 8; ++i) {
        int r = i*4 + wave;
        f4 av = ((const f4*)(tile + (size_t)r*dd))[lane];
        f4 pr = av * qv;
        float p = pr.x + pr.y + pr.z + pr.w;
        #pragma unroll
        for (int off = 32; off > 0; off >>= 1) p += __shfl_xor(p, off);
        if (lane == 0) esc[r] = __expf(p);
    }
    __syncthreads();
    if (t < 32) {
        float v = esc[t];
        #pragma unroll
        for (int off = 16; off > 0; off >>= 1) v += __shfl_xor(v, off);
        if (t == 0) ws[OFF_SUMP + which*1024 + b*128 + mc] = v;
    }
    if (which == 0) {
        float acc = 0.f;
        #pragma unroll 8
        for (int i = 0; i < 32; ++i) acc += esc[i] * tile[(size_t)i*dd + t];
        ws[OFF_PRET + (size_t)(b*128 + mc)*dd + t] = acc;
    } else if (t < 32) {
        ws[OFF_SC + (size_t)b*MM + mc*32 + t] = esc[t];
    }
}

// K7: SUMP reduce + PRET reduce + normalize + Wo matvec + combo. grid = 128.
__global__ void k7(const float* __restrict__ Wo, const float* __restrict__ bo,
                   float* __restrict__ ws) {
    __shared__ float ret[dd];
    __shared__ float red[256];
    __shared__ float ssum;
    int blk = blockIdx.x;
    int cb = blk & 15;
    int b = blk >> 4;
    int t = threadIdx.x;
    if (t < 64) {
        float v = ws[OFF_SUMP + b*128 + t] + ws[OFF_SUMP + b*128 + 64 + t];
        #pragma unroll
        for (int off = 32; off > 0; off >>= 1) v += __shfl_xor(v, off);
        if (t == 0) ssum = v;
    } else if (t < 128 && cb == 0) {
        int u = t - 64;
        float v = ws[OFF_SUMP + 1024 + b*128 + u] + ws[OFF_SUMP + 1024 + b*128 + 64 + u];
        #pragma unroll
        for (int off = 32; off > 0; off >>= 1) v += __shfl_xor(v, off);
        if (t == 64) ws[OFF_COMBO + b] = 0.05f * ws[OFF_GATE + b] / v;
    }
    float acc0 = 0.f;
    #pragma unroll 8
    for (int mc = 0; mc < 128; ++mc)
        acc0 += ws[OFF_PRET + (size_t)(b*128 + mc)*dd + t];
    __syncthreads();
    ret[t] = acc0 / ssum;
    __syncthreads();
    int c = t & 63, jr = t >> 6;
    float acc = 0.f;
    #pragma unroll 8
    for (int jj = 0; jj < 64; ++jj) {
        int j = jr*64 + jj;
        acc += ret[j] * Wo[(size_t)j*DD + cb*64 + c];
    }
    red[t] = acc; __syncthreads();
    if (t < 64) {
        ws[OFF_ROUT + (size_t)b*DD + cb*64 + t] =
            red[t] + red[t+64] + red[t+128] + red[t+192] + bo[cb*64 + t];
    }
}

// K8: fused elementwise outputs, block-range split, fully unrolled (b == it).
// blocks 0..2047: x_aug (8 iters, stride = one batch's S*D/4).
// blocks 2048..3071: memory EMA (8 iters, stride = one batch's M*d/4).
__global__ void k8(const float* __restrict__ x, const float* __restrict__ memory,
                   const float* __restrict__ ws, float* __restrict__ out) {
    int blk = blockIdx.x;
    int t = threadIdx.x;
    if (blk < 2048) {
        const f4* x4 = (const f4*)x;
        const f4* r4 = (const f4*)(ws + OFF_ROUT);
        f4* o4 = (f4*)out;
        int base = blk*256 + t;                 // < 524288 = S*D/4
        int c = base & 255;
        #pragma unroll
        for (int it = 0; it < 8; ++it) {        // it == batch b
            int i = base + it*(SS*DD/4);
            f4 o = x4[i] + r4[(it << 8) + c];
            __builtin_nontemporal_store(o, &o4[i]);
        }
    } else {
        const f4* m4 = (const f4*)memory;
        const f4* w4 = (const f4*)(ws + OFF_WV);
        f4* o4 = (f4*)out + (BB*SS*DD/4);
        int base = (blk - 2048)*256 + t;        // < 262144 = M*d/4
        int m = base >> 6;
        int d4 = base & 63;
        #pragma unroll
        for (int it = 0; it < 8; ++it) {        // it == batch b
            int j = base + it*(MM*dd/4);
            float coeff = ws[OFF_COMBO + it] * ws[OFF_SC + it*MM + m];
            f4 o = 0.95f*m4[j] + coeff*w4[(it << 6) + d4];
            __builtin_nontemporal_store(o, &o4[j]);
        }
    }
}

extern "C" void kernel_launch(void* const* d_in, const int* in_sizes, int n_in,
                              void* d_out, int out_size, void* d_ws, size_t ws_size,
                              hipStream_t stream) {
    const float* x      = (const float*)d_in[0];
    const float* memory = (const float*)d_in[1];
    const float* Wq     = (const float*)d_in[2];
    const float* bq     = (const float*)d_in[3];
    const float* Wv     = (const float*)d_in[4];
    const float* bv     = (const float*)d_in[5];
    const float* Wo     = (const float*)d_in[6];
    const float* bo     = (const float*)d_in[7];
    const float* Wg     = (const float*)d_in[8];
    const float* bg     = (const float*)d_in[9];
    float* out = (float*)d_out;
    float* ws  = (float*)d_ws;

    k1<<<BB*NCH, 256, 0, stream>>>(x, ws);
    k23<<<72, 512, 0, stream>>>(Wq, bq, Wv, bv, Wg, bg, ws);
    k45<<<2048, 256, 0, stream>>>(memory, ws);
    k7<<<BB*16, 256, 0, stream>>>(Wo, bo, ws);
    k8<<<3072, 256, 0, stream>>>(x, memory, ws, out);
}